// Round 2
// baseline (101.563 us; speedup 1.0000x reference)
//
#include <hip/hip_runtime.h>
#include <hip/hip_bf16.h>

// Problem: B=8, CIN=32, H=W=28, COUT=64, 3x3, pad=1, stride=1. fp32 in/out.
// out[b,o,h,w] = sum_{i,j,c} E(b,c,h+i-1,w+j-1) * (exp(kf[(i*3+j)*32+c, o]+5) - dw)
//                + (288*dw - dx*colsum[o] + bias[o])
// E = x+1 in-bounds, 1 at padded positions (pad applied to ln(x+1), exp(0)=1).

#define NB    8
#define NC    32
#define NH    28
#define NW    28
#define NO    64
#define NTAPS 288   // 3*3*32
#define NWGT  (NTAPS * NO)   // 18432

// --- Kernel 1 (1 block): W2 = exp(kf+5)-dw -> ws[0:18432]; const[o] -> ws[18432:18496]
__global__ __launch_bounds__(256) void prep_weights(
    const float* __restrict__ k,     // [288,64]
    const float* __restrict__ bias,  // [64]
    const float* __restrict__ dxa,   // scalar
    const float* __restrict__ dwa,   // scalar
    float* __restrict__ ws)
{
    const int t  = threadIdx.x;
    const float dw = dwa[0];
    const float dx = dxa[0];

    for (int idx = t; idx < NWGT; idx += 256)
        ws[idx] = __expf(k[idx] + 5.0f) - dw;

    if (t < NO) {
        float s = 0.0f;
        for (int r = 0; r < NTAPS; ++r) s += k[r * NO + t];
        ws[NWGT + t] = 288.0f * dw - dx * s + bias[t];
    }
}

// --- Kernel 2: grid = B*H blocks; one (b,h) output row pair-set per block.
__global__ __launch_bounds__(256) void fused_lse_conv(
    const float* __restrict__ x,     // [8,32,28,28]
    const float* __restrict__ ws,    // W2[18432] + consts[64]
    float* __restrict__ out)         // [8,64,28,28]
{
    __shared__ float W2s[NWGT];      // 73728 B
    __shared__ float Es[3][NC][30];  // 11520 B: rows h-1..h+1, cols -1..28
    __shared__ float consts[NO];     // 256 B

    const int t   = threadIdx.x;
    const int blk = blockIdx.x;      // 0..223
    const int b   = blk / NH;
    const int h   = blk % NH;

    // Stage W2 (L2-resident after first touch) with float4 loads.
    const float4* w4 = (const float4*)ws;
    for (int idx = t; idx < NWGT / 4; idx += 256)
        ((float4*)W2s)[idx] = w4[idx];

    if (t < NO) consts[t] = ws[NWGT + t];

    // E halo tile (pad value = 1.0)
    for (int e = t; e < 3 * NC * 30; e += 256) {
        int i   = e / (NC * 30);
        int rem = e % (NC * 30);
        int c   = rem / 30;
        int col = rem % 30;
        int hh  = h - 1 + i;
        int wwc = col - 1;
        float v = 1.0f;
        if (hh >= 0 && hh < NH && wwc >= 0 && wwc < NW)
            v = x[((b * NC + c) * NH + hh) * NW + wwc] + 1.0f;
        Es[i][c][col] = v;
    }
    __syncthreads();

    // Each thread: one o (= lane -> conflict-free W2 reads), 7 consecutive w
    // (Es reads wave-uniform -> broadcast).
    const int o  = t & 63;
    const int w0 = (t >> 6) * 7;     // 0,7,14,21

    float acc[7];
    #pragma unroll
    for (int q = 0; q < 7; ++q) acc[q] = 0.0f;

    for (int i = 0; i < 3; ++i) {
        #pragma unroll 4
        for (int c = 0; c < NC; ++c) {
            float e[9];
            #pragma unroll
            for (int q = 0; q < 9; ++q) e[q] = Es[i][c][w0 + q];
            #pragma unroll
            for (int j = 0; j < 3; ++j) {
                float w2 = W2s[((i * 3 + j) * NC + c) * NO + o];
                #pragma unroll
                for (int q = 0; q < 7; ++q) acc[q] = fmaf(e[j + q], w2, acc[q]);
            }
        }
    }

    const float cst = consts[o];
    const long obase = ((long)(b * NO + o) * NH + h) * NW + w0;
    #pragma unroll
    for (int q = 0; q < 7; ++q)
        out[obase + q] = acc[q] + cst;
}

extern "C" void kernel_launch(void* const* d_in, const int* in_sizes, int n_in,
                              void* d_out, int out_size, void* d_ws, size_t ws_size,
                              hipStream_t stream) {
    const float* x    = (const float*)d_in[0];
    const float* k    = (const float*)d_in[1];
    const float* bias = (const float*)d_in[2];
    const float* dxa  = (const float*)d_in[3];
    const float* dwa  = (const float*)d_in[4];
    float* out        = (float*)d_out;
    float* ws         = (float*)d_ws;

    prep_weights<<<1, 256, 0, stream>>>(k, bias, dxa, dwa, ws);
    fused_lse_conv<<<NB * NH, 256, 0, stream>>>(x, ws, out);
}

// Round 3
// 98.616 us; speedup vs baseline: 1.0299x; 1.0299x over previous
//
#include <hip/hip_runtime.h>
#include <hip/hip_bf16.h>

// Problem: B=8, CIN=32, H=W=28, COUT=64, 3x3, pad=1, stride=1. fp32 in/out.
// out[b,o,h,w] = sum_{i,j,c} E(b,c,h+i-1,w+j-1) * W2[(i*3+j)*32+c][o] + const[o]
//   W2 = exp(kf+5) - dw;  E = x+1 in-bounds, 1 at pads
//   const[o] = 288*dw - dx*colsum[o] + bias[o]

#define NB    8
#define NC    32
#define NH    28
#define NW    28
#define NO    64
#define NTAPS 288
#define NWGT  (NTAPS * NO)        // 18432 floats: W2[r][o]
#define CBASE NWGT                // 18432: consts[64]
#define EBASE (NWGT + 128)        // 18560 (256B-aligned): E_pad[8][32][30][32]
#define EROW  32                  // padded row stride
#define NE    (NB * NC * 30 * EROW)  // 245760

// --- Kernel 1: fill E_pad, W2, consts. grid = 256 x 256.
__global__ __launch_bounds__(256) void prep(
    const float* __restrict__ x,     // [8,32,28,28]
    const float* __restrict__ k,     // [288,64]
    const float* __restrict__ bias,  // [64]
    const float* __restrict__ dxa,
    const float* __restrict__ dwa,
    float* __restrict__ ws)
{
    const int t   = threadIdx.x;
    const int blk = blockIdx.x;
    const float dw = dwa[0];
    const float dx = dxa[0];

    // E_pad fill (all blocks, grid-stride). layout [b][c][hp(30)][wp(32)]
    for (int e = blk * 256 + t; e < NE; e += 256 * 256) {
        int b    = e / (NC * 30 * EROW);
        int rem  = e % (NC * 30 * EROW);
        int c    = rem / (30 * EROW);
        int rem2 = rem % (30 * EROW);
        int hp   = rem2 / EROW;
        int wp   = rem2 % EROW;
        int hh   = hp - 1, ww = wp - 1;
        float v  = 1.0f;
        if (hh >= 0 && hh < NH && ww >= 0 && ww < NW)
            v = x[((b * NC + c) * NH + hh) * NW + ww] + 1.0f;
        ws[EBASE + e] = v;
    }

    // W2 (blocks 0..71, 256 elems each)
    if (blk < 72) {
        int idx = blk * 256 + t;
        ws[idx] = __expf(k[idx] + 5.0f) - dw;
    }

    // consts (block 72): o = t>>2, 4 partial sums combined via shfl
    if (blk == 72) {
        int o = t >> 2, p = t & 3;
        float s = 0.0f;
        for (int r = p; r < NTAPS; r += 4) s += k[r * NO + o];
        s += __shfl_xor(s, 1);
        s += __shfl_xor(s, 2);
        if (p == 0) ws[CBASE + o] = 288.0f * dw - dx * s + bias[o];
    }
}

// --- Kernel 2: grid = B*H = 224 blocks, 256 threads, NO LDS.
// thread = (o = t&63, w-group of 7). E reads wave-uniform -> scalar (SMEM) path;
// W2 reads lane-coalesced 256B/wave from L2 (vmcnt pipe).
__global__ __launch_bounds__(256) void conv(
    const float* __restrict__ ws,
    float* __restrict__ out)
{
    const int t = threadIdx.x;
    const int b = blockIdx.x / NH;
    const int h = blockIdx.x % NH;
    const int o = t & 63;
    const int w0 = __builtin_amdgcn_readfirstlane((t >> 6) * 7);  // 0,7,14,21

    const float* __restrict__ W2 = ws;
    const float* __restrict__ E  = ws + EBASE;

    float acc[7];
    #pragma unroll
    for (int q = 0; q < 7; ++q) acc[q] = 0.0f;

    #pragma unroll
    for (int i = 0; i < 3; ++i) {
        // row base for c=0: E[((b*32+0)*30 + (h+i))*32 + w0]
        const float* Erow0 = E + ((long)(b * NC) * 30 + (h + i)) * EROW + w0;
        const float* W2r0  = W2 + (i * 3) * NC * NO + o;
        #pragma unroll 4
        for (int c = 0; c < NC; ++c) {
            const float* Erow = Erow0 + c * (30 * EROW);
            float e[9];
            #pragma unroll
            for (int m = 0; m < 9; ++m) e[m] = Erow[m];
            #pragma unroll
            for (int j = 0; j < 3; ++j) {
                float w2 = W2r0[(j * NC + c) * NO];
                #pragma unroll
                for (int q = 0; q < 7; ++q) acc[q] = fmaf(e[j + q], w2, acc[q]);
            }
        }
    }

    const float cst = ws[CBASE + o];
    const long obase = ((long)(b * NO + o) * NH + h) * NW + w0;
    #pragma unroll
    for (int q = 0; q < 7; ++q)
        out[obase + q] = acc[q] + cst;
}

extern "C" void kernel_launch(void* const* d_in, const int* in_sizes, int n_in,
                              void* d_out, int out_size, void* d_ws, size_t ws_size,
                              hipStream_t stream) {
    const float* x    = (const float*)d_in[0];
    const float* k    = (const float*)d_in[1];
    const float* bias = (const float*)d_in[2];
    const float* dxa  = (const float*)d_in[3];
    const float* dwa  = (const float*)d_in[4];
    float* out        = (float*)d_out;
    float* ws         = (float*)d_ws;

    prep<<<256, 256, 0, stream>>>(x, k, bias, dxa, dwa, ws);
    conv<<<NB * NH, 256, 0, stream>>>(ws, out);
}

// Round 4
// 78.343 us; speedup vs baseline: 1.2964x; 1.2588x over previous
//
#include <hip/hip_runtime.h>
#include <hip/hip_bf16.h>

// Problem: B=8, CIN=32, H=W=28, COUT=64, 3x3, pad=1, stride=1. fp32 in/out.
// out[b,o,h,w] = sum_{i,j,c} E(b,c,h+i-1,w+j-1) * W2[(i*3+j)*32+c][o] + const[o]
//   W2 = exp(kf+5) - dw;  E = x+1 in-bounds, 1 at pads (pad applied to ln(x+1))
//   const[o] = 288*dw - dx*colsum[o] + bias[o]
// Single kernel: no workspace use, one launch. grid = B*H = 224 blocks x 256.

#define NB    8
#define NC    32
#define NH    28
#define NW    28
#define NO    64
#define NTAPS 288
#define NWGT  (NTAPS * NO)   // 18432

__global__ __launch_bounds__(256) void fused_conv(
    const float* __restrict__ x,     // [8,32,28,28]
    const float* __restrict__ k,     // [288,64]
    const float* __restrict__ bias,  // [64]
    const float* __restrict__ dxa,
    const float* __restrict__ dwa,
    float* __restrict__ out)         // [8,64,28,28]
{
    __shared__ float W2s[NWGT];          // 73728 B
    __shared__ float Es[3][NC][30];      // 11520 B: rows h-1..h+1, cols -1..28
    __shared__ float cpart[4][NO];       // 1024 B: colsum partials

    const int t = threadIdx.x;
    const int b = blockIdx.x / NH;
    const int h = blockIdx.x % NH;
    const int o = t & 63;
    const int p = t >> 6;                // wave id 0..3

    const float dw = dwa[0];
    const float dx = dxa[0];

    // --- W2 = exp(k+5) - dw into LDS (coalesced global reads)
    #pragma unroll 8
    for (int q = 0; q < NWGT / 256; ++q) {
        int idx = q * 256 + t;
        W2s[idx] = __expf(k[idx] + 5.0f) - dw;
    }

    // --- colsum partials: wave p sums rows [p*72, p*72+72) of column o
    {
        float s = 0.0f;
        const float* kp = k + p * 72 * NO + o;
        #pragma unroll 8
        for (int r = 0; r < 72; ++r) s += kp[r * NO];
        cpart[p][o] = s;
    }

    // --- E halo tile (pad value = 1.0)
    for (int e = t; e < 3 * NC * 30; e += 256) {
        int i   = e / (NC * 30);
        int rem = e % (NC * 30);
        int c   = rem / 30;
        int col = rem % 30;
        int hh  = h - 1 + i;
        int ww  = col - 1;
        float v = 1.0f;
        if (hh >= 0 && hh < NH && ww >= 0 && ww < NW)
            v = x[((b * NC + c) * NH + hh) * NW + ww] + 1.0f;
        Es[i][c][col] = v;
    }
    __syncthreads();

    // --- conv: thread = (o = lane, 7 consecutive w). W2 reads lane-linear
    //     (conflict-free), E reads wave-uniform (broadcast).
    const int w0 = (t >> 6) * 7;     // 0,7,14,21

    float acc[7];
    #pragma unroll
    for (int q = 0; q < 7; ++q) acc[q] = 0.0f;

    #pragma unroll
    for (int i = 0; i < 3; ++i) {
        #pragma unroll 4
        for (int c = 0; c < NC; ++c) {
            float e[9];
            #pragma unroll
            for (int m = 0; m < 9; ++m) e[m] = Es[i][c][w0 + m];
            #pragma unroll
            for (int j = 0; j < 3; ++j) {
                float w2 = W2s[((i * 3 + j) * NC + c) * NO + o];
                #pragma unroll
                for (int q = 0; q < 7; ++q) acc[q] = fmaf(e[j + q], w2, acc[q]);
            }
        }
    }

    const float cst = 288.0f * dw
                    - dx * (cpart[0][o] + cpart[1][o] + cpart[2][o] + cpart[3][o])
                    + bias[o];
    const long obase = ((long)(b * NO + o) * NH + h) * NW + w0;
    #pragma unroll
    for (int q = 0; q < 7; ++q)
        out[obase + q] = acc[q] + cst;
}

extern "C" void kernel_launch(void* const* d_in, const int* in_sizes, int n_in,
                              void* d_out, int out_size, void* d_ws, size_t ws_size,
                              hipStream_t stream) {
    const float* x    = (const float*)d_in[0];
    const float* k    = (const float*)d_in[1];
    const float* bias = (const float*)d_in[2];
    const float* dxa  = (const float*)d_in[3];
    const float* dwa  = (const float*)d_in[4];
    float* out        = (float*)d_out;

    fused_conv<<<NB * NH, 256, 0, stream>>>(x, k, bias, dxa, dwa, out);
}

// Round 5
// 72.766 us; speedup vs baseline: 1.3957x; 1.0766x over previous
//
#include <hip/hip_runtime.h>
#include <hip/hip_bf16.h>

// Problem: B=8, CIN=32, H=W=28, COUT=64, 3x3, pad=1, stride=1. fp32 in/out.
// out[b,o,h,w] = sum_{i,j,c} E(b,c,h+i-1,w+j-1) * W2[(i*3+j)*32+c][o] + const[o]
//   W2 = exp(kf+5) - dw;  E = x+1 in-bounds, 1 at pads (pad applied to ln(x+1))
//   const[o] = 288*dw - dx*colsum[o] + bias[o]
// Single kernel, grid = B*H = 224 x 256 threads.
// Wave p owns taps with c in [8p, 8p+8) (72 taps); W2 lives in VGPRs (w2r[72]).
// Each thread: lane = o, accumulates all 28 w. Cross-wave reduce via LDS.

#define NB 8
#define NC 32
#define NH 28
#define NW 28
#define NO 64

__global__ __launch_bounds__(256, 1) void fused_conv(
    const float* __restrict__ x,     // [8,32,28,28]
    const float* __restrict__ k,     // [288,64] = [(i*3+j)*32+c][o]
    const float* __restrict__ bias,  // [64]
    const float* __restrict__ dxa,
    const float* __restrict__ dwa,
    float* __restrict__ out)         // [8,64,28,28]
{
    __shared__ float Es[3][NC][32];   // 12288 B: [i][c][col], col 0..29 used
    __shared__ float Rbuf[4][NW][NO]; // 28672 B: tap-partial sums
    __shared__ float kpart[4][NO];    // 1024 B: colsum partials

    const int t    = threadIdx.x;
    const int lane = t & 63;          // = o
    const int p    = t >> 6;          // wave id; owns c in [8p, 8p+8)
    const int b    = blockIdx.x / NH;
    const int h    = blockIdx.x % NH;
    const float dw = dwa[0];
    const float dx = dxa[0];

    // --- W2 into registers (lane-coalesced 256B loads from L2) + colsum partial
    float w2r[72];
    float ksum = 0.0f;
    const float* kbase = k + p * 8 * NO + lane;
    #pragma unroll
    for (int ij = 0; ij < 9; ++ij) {
        #pragma unroll
        for (int cc = 0; cc < 8; ++cc) {
            float kv = kbase[(ij * NC + cc) * NO];
            ksum += kv;
            w2r[ij * 8 + cc] = __expf(kv + 5.0f) - dw;
        }
    }

    // --- Fill OWN E slice [i][8p+cc][col] (720 elems/wave) — no barrier needed:
    //     this wave is the only reader of its c-range.
    for (int e = lane; e < 720; e += 64) {
        int i   = e / 240;
        int rem = e % 240;
        int cc  = rem / 30;
        int col = rem % 30;
        int hh  = h - 1 + i;
        int ww  = col - 1;
        float v = 1.0f;
        if (hh >= 0 && hh < NH && ww >= 0 && ww < NW)
            v = x[((b * NC + (p * 8 + cc)) * NH + hh) * NW + ww] + 1.0f;
        Es[i][p * 8 + cc][col] = v;
    }

    // --- Main loop: 24 (i,cc) iters; E row broadcast via ds_read_b128;
    //     84 FMAs per iter into acc[28].
    float acc[NW];
    #pragma unroll
    for (int w = 0; w < NW; ++w) acc[w] = 0.0f;

    #pragma unroll
    for (int i = 0; i < 3; ++i) {
        #pragma unroll
        for (int cc = 0; cc < 8; ++cc) {
            const float* er = &Es[i][p * 8 + cc][0];  // 128B-aligned row
            float e[30];
            #pragma unroll
            for (int m = 0; m < 7; ++m)
                *(float4*)&e[4 * m] = *(const float4*)&er[4 * m];
            e[28] = er[28];
            e[29] = er[29];
            #pragma unroll
            for (int j = 0; j < 3; ++j) {
                float w2 = w2r[(i * 3 + j) * 8 + cc];
                #pragma unroll
                for (int w = 0; w < NW; ++w)
                    acc[w] = fmaf(e[w + j], w2, acc[w]);
            }
        }
    }

    // --- Cross-wave reduction
    #pragma unroll
    for (int w = 0; w < NW; ++w)
        Rbuf[p][w][lane] = acc[w];     // lane-consecutive: conflict-free
    kpart[p][lane] = ksum;
    __syncthreads();

    const int o  = lane;
    const int w0 = p * 7;              // waves cover w 0..27 in the epilogue
    const float cs  = kpart[0][o] + kpart[1][o] + kpart[2][o] + kpart[3][o];
    const float cst = 288.0f * dw - dx * cs + bias[o];
    const long obase = ((long)(b * NO + o) * NH + h) * NW + w0;
    #pragma unroll
    for (int q = 0; q < 7; ++q) {
        float s = Rbuf[0][w0 + q][o] + Rbuf[1][w0 + q][o]
                + Rbuf[2][w0 + q][o] + Rbuf[3][w0 + q][o];
        out[obase + q] = s + cst;
    }
}

extern "C" void kernel_launch(void* const* d_in, const int* in_sizes, int n_in,
                              void* d_out, int out_size, void* d_ws, size_t ws_size,
                              hipStream_t stream) {
    const float* x    = (const float*)d_in[0];
    const float* k    = (const float*)d_in[1];
    const float* bias = (const float*)d_in[2];
    const float* dxa  = (const float*)d_in[3];
    const float* dwa  = (const float*)d_in[4];
    float* out        = (float*)d_out;

    fused_conv<<<NB * NH, 256, 0, stream>>>(x, k, bias, dxa, dwa, out);
}

// Round 6
// 69.596 us; speedup vs baseline: 1.4593x; 1.0456x over previous
//
#include <hip/hip_runtime.h>
#include <hip/hip_bf16.h>

// Problem: B=8, CIN=32, H=W=28, COUT=64, 3x3, pad=1, stride=1. fp32 in/out.
// Folded form:
//   out[b,o,h,w] = sum_{in-bounds taps r} x_r * w2[r][o]  + S2[o] + const[o]
//   w2 = exp(kf+5) - dw;  S2[o] = sum_{all 288 r} w2[r][o]
//   const[o] = 288*dw - dx*colsum[o] + bias[o]
// (pad taps contribute exactly w2*1, absorbed into S2; in-bounds contribute
//  w2*(x+1) = w2*x + w2 — the +w2 also lands in S2.)
// Single kernel, grid = B*H = 224 x 512 threads (8 waves, 2/SIMD).
// Wave p owns c in [4p,4p+4); w2 lives in VGPRs; x rows read via wave-uniform
// (scalar-path) loads; NO LDS in the main loop.

#define NB 8
#define NC 32
#define NH 28
#define NW 28
#define NO 64

__global__ __launch_bounds__(512, 2) void fused_conv(
    const float* __restrict__ x,     // [8,32,28,28]
    const float* __restrict__ k,     // [288,64] = [(i*3+j)*32+c][o]
    const float* __restrict__ bias,  // [64]
    const float* __restrict__ dxa,
    const float* __restrict__ dwa,
    float* __restrict__ out)         // [8,64,28,28]
{
    __shared__ float Rbuf[8][NW][NO];   // 57344 B: per-wave partial sums
    __shared__ float spart[2][8][NO];   // 4096 B: ksum / S2 partials

    const int t    = threadIdx.x;
    const int lane = t & 63;            // = o
    const int p    = t >> 6;            // wave 0..7; owns c in [4p, 4p+4)
    const int b    = blockIdx.x / NH;
    const int h    = blockIdx.x % NH;
    const float dw = dwa[0];
    const float dx = dxa[0];

    // --- w2 into VGPRs (lane-coalesced 256B loads, L2-resident) + partials
    float w2r[36];
    float ksum = 0.0f, s2 = 0.0f;
    const float* kb = k + p * 4 * NO + lane;
    #pragma unroll
    for (int ij = 0; ij < 9; ++ij) {
        #pragma unroll
        for (int cc = 0; cc < 4; ++cc) {
            float kv = kb[(ij * NC + cc) * NO];
            ksum += kv;
            float w2 = __expf(kv + 5.0f) - dw;
            s2 += w2;
            w2r[ij * 4 + cc] = w2;
        }
    }

    // --- main loop: 12 wave-uniform x-rows, boundary taps skipped (contribute 0)
    float acc[NW];
    #pragma unroll
    for (int w = 0; w < NW; ++w) acc[w] = 0.0f;

    #pragma unroll
    for (int i = 0; i < 3; ++i) {
        const int hh = h - 1 + i;
        if (hh >= 0 && hh < NH) {
            #pragma unroll
            for (int cc = 0; cc < 4; ++cc) {
                const int c = p * 4 + cc;
                const int rowoff =
                    __builtin_amdgcn_readfirstlane(((b * NC + c) * NH + hh) * NW);
                const float* xr = x + rowoff;
                float e[NW];
                #pragma unroll
                for (int m = 0; m < NW; ++m) e[m] = xr[m];

                const float w20 = w2r[(i * 3 + 0) * 4 + cc];
                #pragma unroll
                for (int w = 1; w < NW; ++w) acc[w] = fmaf(e[w - 1], w20, acc[w]);
                const float w21 = w2r[(i * 3 + 1) * 4 + cc];
                #pragma unroll
                for (int w = 0; w < NW; ++w) acc[w] = fmaf(e[w], w21, acc[w]);
                const float w22 = w2r[(i * 3 + 2) * 4 + cc];
                #pragma unroll
                for (int w = 0; w < NW - 1; ++w) acc[w] = fmaf(e[w + 1], w22, acc[w]);
            }
        }
    }

    // --- cross-wave reduction (only LDS use in the kernel)
    #pragma unroll
    for (int w = 0; w < NW; ++w)
        Rbuf[p][w][lane] = acc[w];      // lane-consecutive: conflict-free
    spart[0][p][lane] = ksum;
    spart[1][p][lane] = s2;
    __syncthreads();

    if (p < 7) {                        // 7 waves x 4 w-columns = 28
        const int o  = lane;
        const int w0 = p * 4;
        float cs = 0.0f, ss = 0.0f;
        #pragma unroll
        for (int pp = 0; pp < 8; ++pp) {
            cs += spart[0][pp][o];
            ss += spart[1][pp][o];
        }
        const float cst = 288.0f * dw - dx * cs + bias[o] + ss;
        const long obase = ((long)(b * NO + o) * NH + h) * NW + w0;
        #pragma unroll
        for (int q = 0; q < 4; ++q) {
            float s = 0.0f;
            #pragma unroll
            for (int pp = 0; pp < 8; ++pp) s += Rbuf[pp][w0 + q][o];
            out[obase + q] = s + cst;
        }
    }
}

extern "C" void kernel_launch(void* const* d_in, const int* in_sizes, int n_in,
                              void* d_out, int out_size, void* d_ws, size_t ws_size,
                              hipStream_t stream) {
    const float* x    = (const float*)d_in[0];
    const float* k    = (const float*)d_in[1];
    const float* bias = (const float*)d_in[2];
    const float* dxa  = (const float*)d_in[3];
    const float* dwa  = (const float*)d_in[4];
    float* out        = (float*)d_out;

    fused_conv<<<NB * NH, 512, 0, stream>>>(x, k, bias, dxa, dwa, out);
}

// Round 7
// 67.516 us; speedup vs baseline: 1.5043x; 1.0308x over previous
//
#include <hip/hip_runtime.h>
#include <hip/hip_bf16.h>

// Problem: B=8, CIN=32, H=W=28, COUT=64, 3x3, pad=1, stride=1. fp32 in/out.
// Folded form:
//   out[b,o,h,w] = sum_{in-bounds taps r} x_r * w2[r][o]  + S2[o] + const[o]
//   w2 = exp(kf+5) - dw;  S2[o] = sum_{all 288 r} w2[r][o]
//   const[o] = 288*dw - dx*colsum[o] + bias[o]
// Single kernel, grid = B*H = 224 x 1024 threads (16 waves, 4/SIMD for TLP).
// Wave p owns c in {2p, 2p+1}; w2 in VGPRs (w2r[18]); x rows via wave-uniform
// scalar-path loads; LDS only for the cross-wave reduction.

#define NB 8
#define NC 32
#define NH 28
#define NW 28
#define NO 64

__global__ __launch_bounds__(1024, 1) void fused_conv(
    const float* __restrict__ x,     // [8,32,28,28]
    const float* __restrict__ k,     // [288,64] = [(i*3+j)*32+c][o]
    const float* __restrict__ bias,  // [64]
    const float* __restrict__ dxa,
    const float* __restrict__ dwa,
    float* __restrict__ out)         // [8,64,28,28]
{
    __shared__ float Rbuf[16][NW][NO];  // 114688 B: per-wave partial sums
    __shared__ float spart[2][16][NO];  // 8192 B: ksum / S2 partials

    const int t    = threadIdx.x;
    const int lane = t & 63;            // = o
    const int p    = t >> 6;            // wave 0..15; owns c in {2p, 2p+1}
    const int b    = blockIdx.x / NH;
    const int h    = blockIdx.x % NH;
    const float dw = dwa[0];
    const float dx = dxa[0];

    // --- w2 into VGPRs (lane-coalesced 256B loads, L2-resident) + partials
    float w2r[18];
    float ksum = 0.0f, s2 = 0.0f;
    const float* kb = k + p * 2 * NO + lane;
    #pragma unroll
    for (int ij = 0; ij < 9; ++ij) {
        #pragma unroll
        for (int cc = 0; cc < 2; ++cc) {
            float kv = kb[(ij * NC + cc) * NO];
            ksum += kv;
            float w2 = __expf(kv + 5.0f) - dw;
            s2 += w2;
            w2r[ij * 2 + cc] = w2;
        }
    }

    // --- main loop: 6 wave-uniform x-rows, boundary taps skipped (contribute 0)
    float acc[NW];
    #pragma unroll
    for (int w = 0; w < NW; ++w) acc[w] = 0.0f;

    #pragma unroll
    for (int i = 0; i < 3; ++i) {
        const int hh = h - 1 + i;
        if (hh >= 0 && hh < NH) {
            #pragma unroll
            for (int cc = 0; cc < 2; ++cc) {
                const int c = p * 2 + cc;
                const int rowoff =
                    __builtin_amdgcn_readfirstlane(((b * NC + c) * NH + hh) * NW);
                const float* xr = x + rowoff;
                float e[NW];
                #pragma unroll
                for (int m = 0; m < NW; ++m) e[m] = xr[m];

                const float w20 = w2r[(i * 3 + 0) * 2 + cc];
                #pragma unroll
                for (int w = 1; w < NW; ++w) acc[w] = fmaf(e[w - 1], w20, acc[w]);
                const float w21 = w2r[(i * 3 + 1) * 2 + cc];
                #pragma unroll
                for (int w = 0; w < NW; ++w) acc[w] = fmaf(e[w], w21, acc[w]);
                const float w22 = w2r[(i * 3 + 2) * 2 + cc];
                #pragma unroll
                for (int w = 0; w < NW - 1; ++w) acc[w] = fmaf(e[w + 1], w22, acc[w]);
            }
        }
    }

    // --- cross-wave reduction (only LDS use in the kernel)
    #pragma unroll
    for (int w = 0; w < NW; ++w)
        Rbuf[p][w][lane] = acc[w];      // lane-consecutive: conflict-free
    spart[0][p][lane] = ksum;
    spart[1][p][lane] = s2;
    __syncthreads();

    if (p < 7) {                        // 7 waves x 4 w-columns = 28
        const int o  = lane;
        const int w0 = p * 4;
        float cs = 0.0f, ss = 0.0f;
        #pragma unroll
        for (int pp = 0; pp < 16; ++pp) {
            cs += spart[0][pp][o];
            ss += spart[1][pp][o];
        }
        const float cst = 288.0f * dw - dx * cs + bias[o] + ss;
        const long obase = ((long)(b * NO + o) * NH + h) * NW + w0;
        #pragma unroll
        for (int q = 0; q < 4; ++q) {
            float s = 0.0f;
            #pragma unroll
            for (int pp = 0; pp < 16; ++pp) s += Rbuf[pp][w0 + q][o];
            out[obase + q] = s + cst;
        }
    }
}

extern "C" void kernel_launch(void* const* d_in, const int* in_sizes, int n_in,
                              void* d_out, int out_size, void* d_ws, size_t ws_size,
                              hipStream_t stream) {
    const float* x    = (const float*)d_in[0];
    const float* k    = (const float*)d_in[1];
    const float* bias = (const float*)d_in[2];
    const float* dxa  = (const float*)d_in[3];
    const float* dwa  = (const float*)d_in[4];
    float* out        = (float*)d_out;

    fused_conv<<<NB * NH, 1024, 0, stream>>>(x, k, bias, dxa, dwa, out);
}